// Round 8
// baseline (140.844 us; speedup 1.0000x reference)
//
#include <hip/hip_runtime.h>
#include <hip/hip_bf16.h>

// GAT layer, N=8192, F_IN=256, F_OUT=64.
//  kA : fused independent stages, role by blockIdx parity:
//       even bid -> k2a role: pure-stream mask builder (one adj row per wave),
//         register double-buffered (prefetch next 4KB while balloting current).
//         ML[i][c][q] bit l = adj[i][c*256 + l*4 + q] > 0.
//       odd bid  -> k1 role: scalar Wh = h@W; f,g projections; Bpack (bf16
//         B-frags of Wh).  (round-5-proven body, verbatim)
//  k2b: U = adj@Wh from bitmask via MFMA; masked Gmax; Upack direct. 16 rows/blk.
//       Mask words pre-shifted by sh0 per chunk (compile-time j7 shifts).
//  k3 : fused softmax weights + attention@U via MFMA + denominator; ELU.
//
// Fragment convention (proven rounds 1/3/4/5):
//  element e of lane l <-> k = kblock*32 + (l>>4)*8 + e; A row / B col = l&15;
//  C/D: col = l&15, row = (l>>4)*4 + reg.
//  Bpack/Upack: frag[(kb*4+b)*64 + lane][e]  (s16x8 per lane)
// Mask bit for (row i, col j): word ML[i*128 + (j>>8)*4 + (j&3)], bit (j>>2)&63.
//  For fragment element (r, jb, kg, e): word (jb>>3)*4 + (e&3),
//  shift = (jb&7)*8 + kg*2 + (e>>2). We pre-shift by sh0=kg*2 per chunk.

#define N 8192

typedef float f32x4 __attribute__((ext_vector_type(4)));
typedef short s16x8 __attribute__((ext_vector_type(8)));
typedef unsigned long long u64;
typedef u64 u64x2 __attribute__((ext_vector_type(2)));

__device__ __forceinline__ unsigned short f2bf(float x) {
  unsigned u = __float_as_uint(x);
  u += 0x7FFFu + ((u >> 16) & 1u);   // RNE
  return (unsigned short)(u >> 16);
}
__device__ __forceinline__ unsigned pack2(unsigned short lo, unsigned short hi) {
  return (unsigned)lo | ((unsigned)hi << 16);
}

#define MFMA __builtin_amdgcn_mfma_f32_16x16x32_bf16

// ---------------- kA: fused k2a (even bid) + k1 (odd bid) ----------------
__global__ __launch_bounds__(256) void kA(const float* __restrict__ adj,
                                          const float* __restrict__ h,
                                          const float* __restrict__ W,
                                          const float* __restrict__ a,
                                          u64* __restrict__ ML,
                                          unsigned short* __restrict__ Bpack,
                                          float* __restrict__ f,
                                          float* __restrict__ g) {
  const int l = threadIdx.x & 63;
  const int w = threadIdx.x >> 6;
  const int bid = blockIdx.x;
  if ((bid & 1) == 0) {
    // ----- k2a role: register double-buffered stream -----
    const int i = ((bid >> 1) << 2) + w;   // one row per wave
    const float* ap = adj + (size_t)i * N + (l << 2);
    u64* mp = ML + (size_t)i * 128;
    f32x4 v0 = *(const f32x4*)(ap);
    f32x4 v1 = *(const f32x4*)(ap + 256);
    f32x4 v2 = *(const f32x4*)(ap + 512);
    f32x4 v3 = *(const f32x4*)(ap + 768);
    for (int cc = 0; cc < 32; cc += 4) {
      const int cn = (cc < 28) ? (cc + 4) : cc;   // last iter: L1-hot reload
      f32x4 n0 = *(const f32x4*)(ap + ((cn + 0) << 8));
      f32x4 n1 = *(const f32x4*)(ap + ((cn + 1) << 8));
      f32x4 n2 = *(const f32x4*)(ap + ((cn + 2) << 8));
      f32x4 n3 = *(const f32x4*)(ap + ((cn + 3) << 8));
      u64 b0  = __ballot(v0.x > 0.f), b1  = __ballot(v0.y > 0.f);
      u64 b2  = __ballot(v0.z > 0.f), b3  = __ballot(v0.w > 0.f);
      u64 b4  = __ballot(v1.x > 0.f), b5  = __ballot(v1.y > 0.f);
      u64 b6  = __ballot(v1.z > 0.f), b7  = __ballot(v1.w > 0.f);
      u64 b8  = __ballot(v2.x > 0.f), b9  = __ballot(v2.y > 0.f);
      u64 b10 = __ballot(v2.z > 0.f), b11 = __ballot(v2.w > 0.f);
      u64 b12 = __ballot(v3.x > 0.f), b13 = __ballot(v3.y > 0.f);
      u64 b14 = __ballot(v3.z > 0.f), b15 = __ballot(v3.w > 0.f);
      if (l == 0) {
        u64x2* q = (u64x2*)(mp + (cc << 2));
        u64x2 t0; t0.x = b0;  t0.y = b1;  q[0] = t0;
        u64x2 t1; t1.x = b2;  t1.y = b3;  q[1] = t1;
        u64x2 t2; t2.x = b4;  t2.y = b5;  q[2] = t2;
        u64x2 t3; t3.x = b6;  t3.y = b7;  q[3] = t3;
        u64x2 t4; t4.x = b8;  t4.y = b9;  q[4] = t4;
        u64x2 t5; t5.x = b10; t5.y = b11; q[5] = t5;
        u64x2 t6; t6.x = b12; t6.y = b13; q[6] = t6;
        u64x2 t7; t7.x = b14; t7.y = b15; q[7] = t7;
      }
      v0 = n0; v1 = n1; v2 = n2; v3 = n3;
    }
  } else {
    // ----- k1 role (round-5-proven body) -----
    const int i = ((bid >> 1) << 2) + w;   // row
    const float* hrow = h + (size_t)i * 256;
    float acc = 0.f;
#pragma unroll 4
    for (int kb = 0; kb < 64; ++kb) {
      f32x4 hv = *(const f32x4*)(hrow + (kb << 2));
      acc += hv.x * W[((kb << 2) + 0) * 64 + l];
      acc += hv.y * W[((kb << 2) + 1) * 64 + l];
      acc += hv.z * W[((kb << 2) + 2) * 64 + l];
      acc += hv.w * W[((kb << 2) + 3) * 64 + l];
    }
    float s1 = acc * a[l];
    float s2 = acc * a[64 + l];
#pragma unroll
    for (int d = 32; d > 0; d >>= 1) {
      s1 += __shfl_xor(s1, d);
      s2 += __shfl_xor(s2, d);
    }
    if (l == 0) { f[i] = s1; g[i] = s2; }
    const int kb = i >> 5;
    const int b = l >> 4;
    const int lp = (l & 15) | (((i >> 3) & 3) << 4);
    const int e = i & 7;
    Bpack[(((size_t)(kb * 4 + b)) * 64 + lp) * 8 + e] = f2bf(acc);
  }
}

// ---------------- k2b: U = adj@Wh from mask + Gmax; Upack direct ----------------
__global__ __launch_bounds__(512, 4) void k2b(const u64* __restrict__ ML,
                                              const unsigned short* __restrict__ Bpack,
                                              const float* __restrict__ g,
                                              unsigned short* __restrict__ Upack,
                                              float* __restrict__ Gmax) {
  __shared__ float red[8][64][16];   // 32 KB
  __shared__ float gred[8][16];
  const int l = threadIdx.x & 63;
  const int w = threadIdx.x >> 6;
  const int i0 = blockIdx.x << 4;          // 16 rows/block
  const int r = l & 15, kg = l >> 4;
  const s16x8* Bv = (const s16x8*)Bpack;
  const u64x2* mrow = (const u64x2*)(ML + (size_t)(i0 + r) * 128);
  const int sh0 = kg << 1;
  f32x4 acc0 = {0.f,0.f,0.f,0.f}, acc1 = acc0, acc2 = acc0, acc3 = acc0;
  float gmx = -INFINITY;
  for (int cc = 0; cc < 4; ++cc) {
    const int c = (w << 2) + cc;           // chunk of 256 cols
    u64x2 m01 = mrow[(c << 1)], m23 = mrow[(c << 1) + 1];
    const u64 wq0 = m01.x >> sh0, wq1 = m01.y >> sh0,
              wq2 = m23.x >> sh0, wq3 = m23.y >> sh0;
#pragma unroll
    for (int j7 = 0; j7 < 8; ++j7) {
      const int jb = (c << 3) + j7;
      f32x4 g0 = *(const f32x4*)(g + (jb << 5) + (kg << 3));
      f32x4 g1 = *(const f32x4*)(g + (jb << 5) + (kg << 3) + 4);
      const unsigned bit0 = (unsigned)(wq0 >> (j7 << 3)) & 1u;
      const unsigned bit1 = (unsigned)(wq1 >> (j7 << 3)) & 1u;
      const unsigned bit2 = (unsigned)(wq2 >> (j7 << 3)) & 1u;
      const unsigned bit3 = (unsigned)(wq3 >> (j7 << 3)) & 1u;
      const unsigned bit4 = (unsigned)(wq0 >> ((j7 << 3) + 1)) & 1u;
      const unsigned bit5 = (unsigned)(wq1 >> ((j7 << 3) + 1)) & 1u;
      const unsigned bit6 = (unsigned)(wq2 >> ((j7 << 3) + 1)) & 1u;
      const unsigned bit7 = (unsigned)(wq3 >> ((j7 << 3) + 1)) & 1u;
      s16x8 af;
      af[0] = bit0 ? (short)0x3F80 : (short)0;
      af[1] = bit1 ? (short)0x3F80 : (short)0;
      af[2] = bit2 ? (short)0x3F80 : (short)0;
      af[3] = bit3 ? (short)0x3F80 : (short)0;
      af[4] = bit4 ? (short)0x3F80 : (short)0;
      af[5] = bit5 ? (short)0x3F80 : (short)0;
      af[6] = bit6 ? (short)0x3F80 : (short)0;
      af[7] = bit7 ? (short)0x3F80 : (short)0;
      if (bit0) gmx = fmaxf(gmx, g0.x);
      if (bit1) gmx = fmaxf(gmx, g0.y);
      if (bit2) gmx = fmaxf(gmx, g0.z);
      if (bit3) gmx = fmaxf(gmx, g0.w);
      if (bit4) gmx = fmaxf(gmx, g1.x);
      if (bit5) gmx = fmaxf(gmx, g1.y);
      if (bit6) gmx = fmaxf(gmx, g1.z);
      if (bit7) gmx = fmaxf(gmx, g1.w);
      const size_t bi = ((size_t)jb << 8) + l;
      s16x8 f0 = Bv[bi], f1 = Bv[bi + 64], f2 = Bv[bi + 128], f3 = Bv[bi + 192];
      acc0 = MFMA(af, f0, acc0, 0, 0, 0);
      acc1 = MFMA(af, f1, acc1, 0, 0, 0);
      acc2 = MFMA(af, f2, acc2, 0, 0, 0);
      acc3 = MFMA(af, f3, acc3, 0, 0, 0);
    }
  }
  gmx = fmaxf(gmx, __shfl_xor(gmx, 16));
  gmx = fmaxf(gmx, __shfl_xor(gmx, 32));
  if (l < 16) gred[w][l] = gmx;
#pragma unroll
  for (int q = 0; q < 4; ++q) {
    red[w][l][q] = acc0[q]; red[w][l][4 + q] = acc1[q];
    red[w][l][8 + q] = acc2[q]; red[w][l][12 + q] = acc3[q];
  }
  __syncthreads();
  const int tl = threadIdx.x & 63;
  const int b = (threadIdx.x >> 6) & 3;
  const int sE = threadIdx.x >> 8;
  const int reg0 = sE << 1;
  float u0 = 0.f, u1 = 0.f;
#pragma unroll
  for (int w8 = 0; w8 < 8; ++w8) {
    u0 += red[w8][tl][(b << 2) + reg0];
    u1 += red[w8][tl][(b << 2) + reg0 + 1];
  }
  const int k0 = i0 + ((tl >> 4) << 2) + reg0;
  const unsigned pkv = pack2(f2bf(u0), f2bf(u1));
  const int kbD = k0 >> 5, lgrp = (k0 >> 3) & 3, e0 = k0 & 7;
  *(unsigned*)((char*)Upack +
      ((size_t)((kbD << 2) + b) * 64 + ((tl & 15) | (lgrp << 4))) * 16 + (e0 << 1)) = pkv;
  if (threadIdx.x < 16) {
    float gm = gred[0][threadIdx.x];
#pragma unroll
    for (int w8 = 1; w8 < 8; ++w8) gm = fmaxf(gm, gred[w8][threadIdx.x]);
    Gmax[i0 + threadIdx.x] = gm;
  }
}

// ---------------- k3: fused softmax + attention@U + ELU ----------------
__global__ __launch_bounds__(512, 4) void k3(const u64* __restrict__ ML,
                                             const unsigned short* __restrict__ Upack,
                                             const float* __restrict__ f,
                                             const float* __restrict__ g,
                                             const float* __restrict__ Gmax,
                                             float* __restrict__ out) {
  __shared__ float red[8][64][16];   // 32 KB
  __shared__ float wred[8][16];
  const int l = threadIdx.x & 63;
  const int w = threadIdx.x >> 6;
  const int i0 = blockIdx.x << 4;
  const int r = l & 15, kg = l >> 4;
  const float fi = f[i0 + r];
  float m = fi + Gmax[i0 + r];
  m = fmaxf(m, 0.2f * m);                  // m_i = leaky(f_i + Gmax_i)
  const s16x8* Uv = (const s16x8*)Upack;
  const u64x2* mrow = (const u64x2*)(ML + (size_t)(i0 + r) * 128);
  const int sh0 = kg << 1;
  f32x4 acc0 = {0.f,0.f,0.f,0.f}, acc1 = acc0, acc2 = acc0, acc3 = acc0;
  float wsum = 0.f;
  for (int cc = 0; cc < 4; ++cc) {
    const int c = (w << 2) + cc;
    u64x2 m01 = mrow[(c << 1)], m23 = mrow[(c << 1) + 1];
    const u64 wq0 = m01.x >> sh0, wq1 = m01.y >> sh0,
              wq2 = m23.x >> sh0, wq3 = m23.y >> sh0;
#pragma unroll
    for (int j7 = 0; j7 < 8; ++j7) {
      const int jb = (c << 3) + j7;
      f32x4 g0 = *(const f32x4*)(g + (jb << 5) + (kg << 3));
      f32x4 g1 = *(const f32x4*)(g + (jb << 5) + (kg << 3) + 4);
      s16x8 pf;
      float wt;
#define K3W(idx, wq, sh, gv) {                                  \
      const unsigned bit_ = (unsigned)((wq) >> (sh)) & 1u;      \
      float x_ = fi + (gv);                                     \
      float ev_ = fmaxf(x_, 0.2f * x_);                         \
      wt = __expf(ev_ - m);                                     \
      wt = bit_ ? wt : 0.f;                                     \
      wsum += wt; pf[idx] = (short)f2bf(wt); }
      K3W(0, wq0, (j7 << 3),     g0.x)
      K3W(1, wq1, (j7 << 3),     g0.y)
      K3W(2, wq2, (j7 << 3),     g0.z)
      K3W(3, wq3, (j7 << 3),     g0.w)
      K3W(4, wq0, (j7 << 3) + 1, g1.x)
      K3W(5, wq1, (j7 << 3) + 1, g1.y)
      K3W(6, wq2, (j7 << 3) + 1, g1.z)
      K3W(7, wq3, (j7 << 3) + 1, g1.w)
#undef K3W
      const size_t bi = ((size_t)jb << 8) + l;
      s16x8 f0 = Uv[bi], f1 = Uv[bi + 64], f2 = Uv[bi + 128], f3 = Uv[bi + 192];
      acc0 = MFMA(pf, f0, acc0, 0, 0, 0);
      acc1 = MFMA(pf, f1, acc1, 0, 0, 0);
      acc2 = MFMA(pf, f2, acc2, 0, 0, 0);
      acc3 = MFMA(pf, f3, acc3, 0, 0, 0);
    }
  }
  wsum += __shfl_xor(wsum, 16);
  wsum += __shfl_xor(wsum, 32);
  if (l < 16) wred[w][l] = wsum;
#pragma unroll
  for (int q = 0; q < 4; ++q) {
    red[w][l][q] = acc0[q]; red[w][l][4 + q] = acc1[q];
    red[w][l][8 + q] = acc2[q]; red[w][l][12 + q] = acc3[q];
  }
  __syncthreads();
  const int tl = threadIdx.x & 63;
  const int b = (threadIdx.x >> 6) & 3;
  const int sE = threadIdx.x >> 8;
#pragma unroll
  for (int q = 0; q < 2; ++q) {
    const int reg = (sE << 1) + q;
    const int idx = (b << 2) + reg;
    const int row = ((tl >> 4) << 2) + reg;
    float sv = 0.f, dv = 0.f;
#pragma unroll
    for (int w8 = 0; w8 < 8; ++w8) {
      sv += red[w8][tl][idx];
      dv += wred[w8][row];
    }
    dv = (dv > 0.f) ? dv : 1.f;            // defensive: avoid 0/0
    float v = sv / dv;
    v = (v > 0.f) ? v : (__expf(v) - 1.f); // ELU
    out[(size_t)(i0 + row) * 64 + (b << 4) + (tl & 15)] = v;
  }
}

extern "C" void kernel_launch(void* const* d_in, const int* in_sizes, int n_in,
                              void* d_out, int out_size, void* d_ws, size_t ws_size,
                              hipStream_t stream) {
  const float* h   = (const float*)d_in[0];
  const float* adj = (const float*)d_in[1];
  const float* W   = (const float*)d_in[2];
  const float* a   = (const float*)d_in[3];
  float* out = (float*)d_out;
  char* ws = (char*)d_ws;
  unsigned short* Bpack = (unsigned short*)(ws);                   // 1 MB
  unsigned short* Upack = (unsigned short*)(ws + (1u << 20));      // 1 MB
  float* f    = (float*)(ws + (2u << 20));                         // 32 KB
  float* g    = (float*)(ws + (2u << 20) + 32768u);                // 32 KB
  float* Gmax = (float*)(ws + (2u << 20) + 65536u);                // 32 KB
  u64* ML = (u64*)(ws + (3u << 20));                               // 8 MB

  hipLaunchKernelGGL(kA,  dim3(4096), dim3(256), 0, stream, adj, h, W, a, ML, Bpack, f, g);
  hipLaunchKernelGGL(k2b, dim3(512),  dim3(512), 0, stream, ML, Bpack, g, Upack, Gmax);
  hipLaunchKernelGGL(k3,  dim3(512),  dim3(512), 0, stream, ML, Upack, f, g, Gmax, out);
}

// Round 9
// 138.269 us; speedup vs baseline: 1.0186x; 1.0186x over previous
//
#include <hip/hip_runtime.h>
#include <hip/hip_bf16.h>

// GAT layer, N=8192, F_IN=256, F_OUT=64.
//  kA : fused independent stages, role by blockIdx parity:
//       even bid -> mask builder (one adj row per wave, reg double-buffered).
//         ML[i][c][q] bit l = adj[i][c*256 + l*4 + q] > 0.
//       odd bid  -> k1 role: scalar Wh = h@W; f,g + expg=exp(g), expg2=exp(.2g);
//         Bpack (bf16 B-frags of Wh).
//  k2b: U = adj@Wh from bitmask via MFMA; DUAL row-set (32 rows/block, each
//       fragment load feeds 2 A-fragments); masked Gmax; epilogue writes Upack
//       + per-row softmax factors A=exp(f-m), C=exp(0.2f-m), m=leaky(f+Gmax).
//  k3 : fused softmax + attention@U + ELU, DUAL row-set. Weights factorized:
//       w_ij = (eg_j > exp(-f_i)) ? A_i*eg_j : C_i*eg2_j, masked. No exp in loop.
//
// Fragment convention (proven rounds 1/3/4/5):
//  element e of lane l <-> k = kblock*32 + (l>>4)*8 + e; A row / B col = l&15;
//  C/D: col = l&15, row = (l>>4)*4 + reg.
//  Bpack/Upack: frag[(kb*4+b)*64 + lane][e]  (s16x8 per lane)
// Mask bit for (row i, col j): word ML[i*128 + (j>>8)*4 + (j&3)], bit (j>>2)&63.
//  For fragment element (r, jb, kg, e): word (jb>>3)*4 + (e&3),
//  shift = (jb&7)*8 + kg*2 + (e>>2). Pre-shift by sh0=kg*2 per chunk.

#define N 8192

typedef float f32x4 __attribute__((ext_vector_type(4)));
typedef short s16x8 __attribute__((ext_vector_type(8)));
typedef unsigned long long u64;
typedef u64 u64x2 __attribute__((ext_vector_type(2)));

__device__ __forceinline__ unsigned short f2bf(float x) {
  unsigned u = __float_as_uint(x);
  u += 0x7FFFu + ((u >> 16) & 1u);   // RNE
  return (unsigned short)(u >> 16);
}
__device__ __forceinline__ unsigned pack2(unsigned short lo, unsigned short hi) {
  return (unsigned)lo | ((unsigned)hi << 16);
}

#define MFMA __builtin_amdgcn_mfma_f32_16x16x32_bf16

// ---------------- kA: fused mask-builder (even bid) + k1 (odd bid) ----------------
__global__ __launch_bounds__(256) void kA(const float* __restrict__ adj,
                                          const float* __restrict__ h,
                                          const float* __restrict__ W,
                                          const float* __restrict__ a,
                                          u64* __restrict__ ML,
                                          unsigned short* __restrict__ Bpack,
                                          float* __restrict__ f,
                                          float* __restrict__ g,
                                          float* __restrict__ expg,
                                          float* __restrict__ expg2) {
  const int l = threadIdx.x & 63;
  const int w = threadIdx.x >> 6;
  const int bid = blockIdx.x;
  if ((bid & 1) == 0) {
    const int i = ((bid >> 1) << 2) + w;   // one row per wave
    const float* ap = adj + (size_t)i * N + (l << 2);
    u64* mp = ML + (size_t)i * 128;
    f32x4 v0 = *(const f32x4*)(ap);
    f32x4 v1 = *(const f32x4*)(ap + 256);
    f32x4 v2 = *(const f32x4*)(ap + 512);
    f32x4 v3 = *(const f32x4*)(ap + 768);
    for (int cc = 0; cc < 32; cc += 4) {
      const int cn = (cc < 28) ? (cc + 4) : cc;   // last iter: L1-hot reload
      f32x4 n0 = *(const f32x4*)(ap + ((cn + 0) << 8));
      f32x4 n1 = *(const f32x4*)(ap + ((cn + 1) << 8));
      f32x4 n2 = *(const f32x4*)(ap + ((cn + 2) << 8));
      f32x4 n3 = *(const f32x4*)(ap + ((cn + 3) << 8));
      u64 b0  = __ballot(v0.x > 0.f), b1  = __ballot(v0.y > 0.f);
      u64 b2  = __ballot(v0.z > 0.f), b3  = __ballot(v0.w > 0.f);
      u64 b4  = __ballot(v1.x > 0.f), b5  = __ballot(v1.y > 0.f);
      u64 b6  = __ballot(v1.z > 0.f), b7  = __ballot(v1.w > 0.f);
      u64 b8  = __ballot(v2.x > 0.f), b9  = __ballot(v2.y > 0.f);
      u64 b10 = __ballot(v2.z > 0.f), b11 = __ballot(v2.w > 0.f);
      u64 b12 = __ballot(v3.x > 0.f), b13 = __ballot(v3.y > 0.f);
      u64 b14 = __ballot(v3.z > 0.f), b15 = __ballot(v3.w > 0.f);
      if (l == 0) {
        u64x2* q = (u64x2*)(mp + (cc << 2));
        u64x2 t0; t0.x = b0;  t0.y = b1;  q[0] = t0;
        u64x2 t1; t1.x = b2;  t1.y = b3;  q[1] = t1;
        u64x2 t2; t2.x = b4;  t2.y = b5;  q[2] = t2;
        u64x2 t3; t3.x = b6;  t3.y = b7;  q[3] = t3;
        u64x2 t4; t4.x = b8;  t4.y = b9;  q[4] = t4;
        u64x2 t5; t5.x = b10; t5.y = b11; q[5] = t5;
        u64x2 t6; t6.x = b12; t6.y = b13; q[6] = t6;
        u64x2 t7; t7.x = b14; t7.y = b15; q[7] = t7;
      }
      v0 = n0; v1 = n1; v2 = n2; v3 = n3;
    }
  } else {
    const int i = ((bid >> 1) << 2) + w;   // row
    const float* hrow = h + (size_t)i * 256;
    float acc = 0.f;
#pragma unroll 4
    for (int kb = 0; kb < 64; ++kb) {
      f32x4 hv = *(const f32x4*)(hrow + (kb << 2));
      acc += hv.x * W[((kb << 2) + 0) * 64 + l];
      acc += hv.y * W[((kb << 2) + 1) * 64 + l];
      acc += hv.z * W[((kb << 2) + 2) * 64 + l];
      acc += hv.w * W[((kb << 2) + 3) * 64 + l];
    }
    float s1 = acc * a[l];
    float s2 = acc * a[64 + l];
#pragma unroll
    for (int d = 32; d > 0; d >>= 1) {
      s1 += __shfl_xor(s1, d);
      s2 += __shfl_xor(s2, d);
    }
    if (l == 0) {
      f[i] = s1; g[i] = s2;
      expg[i] = __expf(s2);
      expg2[i] = __expf(0.2f * s2);
    }
    const int kb = i >> 5;
    const int b = l >> 4;
    const int lp = (l & 15) | (((i >> 3) & 3) << 4);
    const int e = i & 7;
    Bpack[(((size_t)(kb * 4 + b)) * 64 + lp) * 8 + e] = f2bf(acc);
  }
}

// ---------------- k2b: U from mask via MFMA, dual row-set; A/C factors ----------------
__global__ __launch_bounds__(512) void k2b(const u64* __restrict__ ML,
                                           const unsigned short* __restrict__ Bpack,
                                           const float* __restrict__ g,
                                           const float* __restrict__ f,
                                           unsigned short* __restrict__ Upack,
                                           float* __restrict__ Av,
                                           float* __restrict__ Cv) {
  __shared__ float red[2][8][64][16];   // 64 KB
  __shared__ float gred[2][8][16];
  const int l = threadIdx.x & 63;
  const int w = threadIdx.x >> 6;
  const int i0 = blockIdx.x << 5;          // 32 rows/block
  const int r = l & 15, kg = l >> 4;
  const s16x8* Bv = (const s16x8*)Bpack;
  const u64x2* mrow0 = (const u64x2*)(ML + (size_t)(i0 + r) * 128);
  const u64x2* mrow1 = (const u64x2*)(ML + (size_t)(i0 + 16 + r) * 128);
  const int sh0 = kg << 1;
  f32x4 x0 = {0.f,0.f,0.f,0.f}, x1 = x0, x2 = x0, x3 = x0;   // set0 accs
  f32x4 y0 = x0, y1 = x0, y2 = x0, y3 = x0;                  // set1 accs
  float gmx0 = -INFINITY, gmx1 = -INFINITY;
  for (int cc = 0; cc < 4; ++cc) {
    const int c = (w << 2) + cc;           // chunk of 256 cols
    u64x2 ma = mrow0[(c << 1)], mb = mrow0[(c << 1) + 1];
    const u64 xa0 = ma.x >> sh0, xa1 = ma.y >> sh0,
              xa2 = mb.x >> sh0, xa3 = mb.y >> sh0;
    u64x2 mc = mrow1[(c << 1)], md = mrow1[(c << 1) + 1];
    const u64 ya0 = mc.x >> sh0, ya1 = mc.y >> sh0,
              ya2 = md.x >> sh0, ya3 = md.y >> sh0;
#pragma unroll
    for (int j7 = 0; j7 < 8; ++j7) {
      const int jb = (c << 3) + j7;
      f32x4 g0 = *(const f32x4*)(g + (jb << 5) + (kg << 3));
      f32x4 g1 = *(const f32x4*)(g + (jb << 5) + (kg << 3) + 4);
      const unsigned p0 = (unsigned)(xa0 >> (j7 << 3)) & 1u;
      const unsigned p1 = (unsigned)(xa1 >> (j7 << 3)) & 1u;
      const unsigned p2 = (unsigned)(xa2 >> (j7 << 3)) & 1u;
      const unsigned p3 = (unsigned)(xa3 >> (j7 << 3)) & 1u;
      const unsigned p4 = (unsigned)(xa0 >> ((j7 << 3) + 1)) & 1u;
      const unsigned p5 = (unsigned)(xa1 >> ((j7 << 3) + 1)) & 1u;
      const unsigned p6 = (unsigned)(xa2 >> ((j7 << 3) + 1)) & 1u;
      const unsigned p7 = (unsigned)(xa3 >> ((j7 << 3) + 1)) & 1u;
      const unsigned q0 = (unsigned)(ya0 >> (j7 << 3)) & 1u;
      const unsigned q1 = (unsigned)(ya1 >> (j7 << 3)) & 1u;
      const unsigned q2 = (unsigned)(ya2 >> (j7 << 3)) & 1u;
      const unsigned q3 = (unsigned)(ya3 >> (j7 << 3)) & 1u;
      const unsigned q4 = (unsigned)(ya0 >> ((j7 << 3) + 1)) & 1u;
      const unsigned q5 = (unsigned)(ya1 >> ((j7 << 3) + 1)) & 1u;
      const unsigned q6 = (unsigned)(ya2 >> ((j7 << 3) + 1)) & 1u;
      const unsigned q7 = (unsigned)(ya3 >> ((j7 << 3) + 1)) & 1u;
      s16x8 af0, af1;
      af0[0] = p0 ? (short)0x3F80 : (short)0;
      af0[1] = p1 ? (short)0x3F80 : (short)0;
      af0[2] = p2 ? (short)0x3F80 : (short)0;
      af0[3] = p3 ? (short)0x3F80 : (short)0;
      af0[4] = p4 ? (short)0x3F80 : (short)0;
      af0[5] = p5 ? (short)0x3F80 : (short)0;
      af0[6] = p6 ? (short)0x3F80 : (short)0;
      af0[7] = p7 ? (short)0x3F80 : (short)0;
      af1[0] = q0 ? (short)0x3F80 : (short)0;
      af1[1] = q1 ? (short)0x3F80 : (short)0;
      af1[2] = q2 ? (short)0x3F80 : (short)0;
      af1[3] = q3 ? (short)0x3F80 : (short)0;
      af1[4] = q4 ? (short)0x3F80 : (short)0;
      af1[5] = q5 ? (short)0x3F80 : (short)0;
      af1[6] = q6 ? (short)0x3F80 : (short)0;
      af1[7] = q7 ? (short)0x3F80 : (short)0;
      if (p0) gmx0 = fmaxf(gmx0, g0.x);
      if (p1) gmx0 = fmaxf(gmx0, g0.y);
      if (p2) gmx0 = fmaxf(gmx0, g0.z);
      if (p3) gmx0 = fmaxf(gmx0, g0.w);
      if (p4) gmx0 = fmaxf(gmx0, g1.x);
      if (p5) gmx0 = fmaxf(gmx0, g1.y);
      if (p6) gmx0 = fmaxf(gmx0, g1.z);
      if (p7) gmx0 = fmaxf(gmx0, g1.w);
      if (q0) gmx1 = fmaxf(gmx1, g0.x);
      if (q1) gmx1 = fmaxf(gmx1, g0.y);
      if (q2) gmx1 = fmaxf(gmx1, g0.z);
      if (q3) gmx1 = fmaxf(gmx1, g0.w);
      if (q4) gmx1 = fmaxf(gmx1, g1.x);
      if (q5) gmx1 = fmaxf(gmx1, g1.y);
      if (q6) gmx1 = fmaxf(gmx1, g1.z);
      if (q7) gmx1 = fmaxf(gmx1, g1.w);
      const size_t bi = ((size_t)jb << 8) + l;
      s16x8 f0 = Bv[bi], f1 = Bv[bi + 64], f2 = Bv[bi + 128], f3 = Bv[bi + 192];
      x0 = MFMA(af0, f0, x0, 0, 0, 0);
      x1 = MFMA(af0, f1, x1, 0, 0, 0);
      x2 = MFMA(af0, f2, x2, 0, 0, 0);
      x3 = MFMA(af0, f3, x3, 0, 0, 0);
      y0 = MFMA(af1, f0, y0, 0, 0, 0);
      y1 = MFMA(af1, f1, y1, 0, 0, 0);
      y2 = MFMA(af1, f2, y2, 0, 0, 0);
      y3 = MFMA(af1, f3, y3, 0, 0, 0);
    }
  }
  gmx0 = fmaxf(gmx0, __shfl_xor(gmx0, 16));
  gmx0 = fmaxf(gmx0, __shfl_xor(gmx0, 32));
  gmx1 = fmaxf(gmx1, __shfl_xor(gmx1, 16));
  gmx1 = fmaxf(gmx1, __shfl_xor(gmx1, 32));
  if (l < 16) { gred[0][w][l] = gmx0; gred[1][w][l] = gmx1; }
#pragma unroll
  for (int q = 0; q < 4; ++q) {
    red[0][w][l][q] = x0[q]; red[0][w][l][4 + q] = x1[q];
    red[0][w][l][8 + q] = x2[q]; red[0][w][l][12 + q] = x3[q];
    red[1][w][l][q] = y0[q]; red[1][w][l][4 + q] = y1[q];
    red[1][w][l][8 + q] = y2[q]; red[1][w][l][12 + q] = y3[q];
  }
  __syncthreads();
  const int tl = threadIdx.x & 63;
  const int b = (threadIdx.x >> 6) & 3;
  const int sE = threadIdx.x >> 8;
  const int reg0 = sE << 1;
#pragma unroll
  for (int s = 0; s < 2; ++s) {
    float u0 = 0.f, u1 = 0.f;
#pragma unroll
    for (int w8 = 0; w8 < 8; ++w8) {
      u0 += red[s][w8][tl][(b << 2) + reg0];
      u1 += red[s][w8][tl][(b << 2) + reg0 + 1];
    }
    const int k0 = i0 + (s << 4) + ((tl >> 4) << 2) + reg0;
    const unsigned pkv = pack2(f2bf(u0), f2bf(u1));
    const int kbD = k0 >> 5, lgrp = (k0 >> 3) & 3, e0 = k0 & 7;
    *(unsigned*)((char*)Upack +
        ((size_t)((kbD << 2) + b) * 64 + ((tl & 15) | (lgrp << 4))) * 16 + (e0 << 1)) = pkv;
  }
  if (threadIdx.x < 32) {
    const int s2 = threadIdx.x >> 4, rr = threadIdx.x & 15;
    float gm = gred[s2][0][rr];
#pragma unroll
    for (int w8 = 1; w8 < 8; ++w8) gm = fmaxf(gm, gred[s2][w8][rr]);
    const int i = i0 + (s2 << 4) + rr;
    const float fv = f[i];
    float mm = fv + gm;
    mm = fmaxf(mm, 0.2f * mm);             // m_i = leaky(f_i + Gmax_i)
    Av[i] = __expf(fv - mm);
    Cv[i] = __expf(0.2f * fv - mm);
  }
}

// ---------------- k3: fused softmax + attention@U + ELU, dual row-set ----------------
__global__ __launch_bounds__(512) void k3(const u64* __restrict__ ML,
                                          const unsigned short* __restrict__ Upack,
                                          const float* __restrict__ f,
                                          const float* __restrict__ expg,
                                          const float* __restrict__ expg2,
                                          const float* __restrict__ Av,
                                          const float* __restrict__ Cv,
                                          float* __restrict__ out) {
  __shared__ float red[2][8][64][16];   // 64 KB
  __shared__ float wred[2][8][16];
  const int l = threadIdx.x & 63;
  const int w = threadIdx.x >> 6;
  const int i0 = blockIdx.x << 5;
  const int r = l & 15, kg = l >> 4;
  const float enf0 = __expf(-f[i0 + r]);
  const float enf1 = __expf(-f[i0 + 16 + r]);
  const float Ar0 = Av[i0 + r],      Cr0 = Cv[i0 + r];
  const float Ar1 = Av[i0 + 16 + r], Cr1 = Cv[i0 + 16 + r];
  const s16x8* Uv = (const s16x8*)Upack;
  const u64x2* mrow0 = (const u64x2*)(ML + (size_t)(i0 + r) * 128);
  const u64x2* mrow1 = (const u64x2*)(ML + (size_t)(i0 + 16 + r) * 128);
  const int sh0 = kg << 1;
  f32x4 x0 = {0.f,0.f,0.f,0.f}, x1 = x0, x2 = x0, x3 = x0;
  f32x4 y0 = x0, y1 = x0, y2 = x0, y3 = x0;
  float ws0 = 0.f, ws1 = 0.f;
  for (int cc = 0; cc < 4; ++cc) {
    const int c = (w << 2) + cc;
    u64x2 ma = mrow0[(c << 1)], mb = mrow0[(c << 1) + 1];
    const u64 xa0 = ma.x >> sh0, xa1 = ma.y >> sh0,
              xa2 = mb.x >> sh0, xa3 = mb.y >> sh0;
    u64x2 mc = mrow1[(c << 1)], md = mrow1[(c << 1) + 1];
    const u64 ya0 = mc.x >> sh0, ya1 = mc.y >> sh0,
              ya2 = md.x >> sh0, ya3 = md.y >> sh0;
#pragma unroll
    for (int j7 = 0; j7 < 8; ++j7) {
      const int jb = (c << 3) + j7;
      f32x4 eg0 = *(const f32x4*)(expg + (jb << 5) + (kg << 3));
      f32x4 eg1 = *(const f32x4*)(expg + (jb << 5) + (kg << 3) + 4);
      f32x4 eh0 = *(const f32x4*)(expg2 + (jb << 5) + (kg << 3));
      f32x4 eh1 = *(const f32x4*)(expg2 + (jb << 5) + (kg << 3) + 4);
      s16x8 pf0, pf1;
#define K3W(pf, idx, wq, sh, egv, ehv, enf, Ar, Cr, wsv) {   \
      const unsigned bit_ = (unsigned)((wq) >> (sh)) & 1u;   \
      const bool sg_ = (egv) > (enf);                        \
      float t_ = sg_ ? (Ar) : (Cr);                          \
      float u_ = sg_ ? (egv) : (ehv);                        \
      float wt_ = t_ * u_;                                   \
      wt_ = bit_ ? wt_ : 0.f;                                \
      wsv += wt_; pf[idx] = (short)f2bf(wt_); }
      K3W(pf0, 0, xa0, (j7 << 3),     eg0.x, eh0.x, enf0, Ar0, Cr0, ws0)
      K3W(pf0, 1, xa1, (j7 << 3),     eg0.y, eh0.y, enf0, Ar0, Cr0, ws0)
      K3W(pf0, 2, xa2, (j7 << 3),     eg0.z, eh0.z, enf0, Ar0, Cr0, ws0)
      K3W(pf0, 3, xa3, (j7 << 3),     eg0.w, eh0.w, enf0, Ar0, Cr0, ws0)
      K3W(pf0, 4, xa0, (j7 << 3) + 1, eg1.x, eh1.x, enf0, Ar0, Cr0, ws0)
      K3W(pf0, 5, xa1, (j7 << 3) + 1, eg1.y, eh1.y, enf0, Ar0, Cr0, ws0)
      K3W(pf0, 6, xa2, (j7 << 3) + 1, eg1.z, eh1.z, enf0, Ar0, Cr0, ws0)
      K3W(pf0, 7, xa3, (j7 << 3) + 1, eg1.w, eh1.w, enf0, Ar0, Cr0, ws0)
      K3W(pf1, 0, ya0, (j7 << 3),     eg0.x, eh0.x, enf1, Ar1, Cr1, ws1)
      K3W(pf1, 1, ya1, (j7 << 3),     eg0.y, eh0.y, enf1, Ar1, Cr1, ws1)
      K3W(pf1, 2, ya2, (j7 << 3),     eg0.z, eh0.z, enf1, Ar1, Cr1, ws1)
      K3W(pf1, 3, ya3, (j7 << 3),     eg0.w, eh0.w, enf1, Ar1, Cr1, ws1)
      K3W(pf1, 4, ya0, (j7 << 3) + 1, eg1.x, eh1.x, enf1, Ar1, Cr1, ws1)
      K3W(pf1, 5, ya1, (j7 << 3) + 1, eg1.y, eh1.y, enf1, Ar1, Cr1, ws1)
      K3W(pf1, 6, ya2, (j7 << 3) + 1, eg1.z, eh1.z, enf1, Ar1, Cr1, ws1)
      K3W(pf1, 7, ya3, (j7 << 3) + 1, eg1.w, eh1.w, enf1, Ar1, Cr1, ws1)
#undef K3W
      const size_t bi = ((size_t)jb << 8) + l;
      s16x8 f0 = Uv[bi], f1 = Uv[bi + 64], f2 = Uv[bi + 128], f3 = Uv[bi + 192];
      x0 = MFMA(pf0, f0, x0, 0, 0, 0);
      x1 = MFMA(pf0, f1, x1, 0, 0, 0);
      x2 = MFMA(pf0, f2, x2, 0, 0, 0);
      x3 = MFMA(pf0, f3, x3, 0, 0, 0);
      y0 = MFMA(pf1, f0, y0, 0, 0, 0);
      y1 = MFMA(pf1, f1, y1, 0, 0, 0);
      y2 = MFMA(pf1, f2, y2, 0, 0, 0);
      y3 = MFMA(pf1, f3, y3, 0, 0, 0);
    }
  }
  ws0 += __shfl_xor(ws0, 16);
  ws0 += __shfl_xor(ws0, 32);
  ws1 += __shfl_xor(ws1, 16);
  ws1 += __shfl_xor(ws1, 32);
  if (l < 16) { wred[0][w][l] = ws0; wred[1][w][l] = ws1; }
#pragma unroll
  for (int q = 0; q < 4; ++q) {
    red[0][w][l][q] = x0[q]; red[0][w][l][4 + q] = x1[q];
    red[0][w][l][8 + q] = x2[q]; red[0][w][l][12 + q] = x3[q];
    red[1][w][l][q] = y0[q]; red[1][w][l][4 + q] = y1[q];
    red[1][w][l][8 + q] = y2[q]; red[1][w][l][12 + q] = y3[q];
  }
  __syncthreads();
  const int tl = threadIdx.x & 63;
  const int b = (threadIdx.x >> 6) & 3;
  const int sE = threadIdx.x >> 8;
#pragma unroll
  for (int s = 0; s < 2; ++s) {
#pragma unroll
    for (int q = 0; q < 2; ++q) {
      const int reg = (sE << 1) + q;
      const int idx = (b << 2) + reg;
      const int row = ((tl >> 4) << 2) + reg;
      float sv = 0.f, dv = 0.f;
#pragma unroll
      for (int w8 = 0; w8 < 8; ++w8) {
        sv += red[s][w8][tl][idx];
        dv += wred[s][w8][row];
      }
      dv = (dv > 0.f) ? dv : 1.f;            // defensive: avoid 0/0
      float v = sv / dv;
      v = (v > 0.f) ? v : (__expf(v) - 1.f); // ELU
      out[(size_t)(i0 + (s << 4) + row) * 64 + (b << 4) + (tl & 15)] = v;
    }
  }
}

extern "C" void kernel_launch(void* const* d_in, const int* in_sizes, int n_in,
                              void* d_out, int out_size, void* d_ws, size_t ws_size,
                              hipStream_t stream) {
  const float* h   = (const float*)d_in[0];
  const float* adj = (const float*)d_in[1];
  const float* W   = (const float*)d_in[2];
  const float* a   = (const float*)d_in[3];
  float* out = (float*)d_out;
  char* ws = (char*)d_ws;
  unsigned short* Bpack = (unsigned short*)(ws);                   // 1 MB
  unsigned short* Upack = (unsigned short*)(ws + (1u << 20));      // 1 MB
  float* f     = (float*)(ws + (2u << 20));                        // 32 KB
  float* g     = (float*)(ws + (2u << 20) + 1u * 32768u);          // 32 KB
  float* expg  = (float*)(ws + (2u << 20) + 2u * 32768u);          // 32 KB
  float* expg2 = (float*)(ws + (2u << 20) + 3u * 32768u);          // 32 KB
  float* Av    = (float*)(ws + (2u << 20) + 4u * 32768u);          // 32 KB
  float* Cv    = (float*)(ws + (2u << 20) + 5u * 32768u);          // 32 KB
  u64* ML = (u64*)(ws + (3u << 20));                               // 8 MB

  hipLaunchKernelGGL(kA,  dim3(4096), dim3(256), 0, stream,
                     adj, h, W, a, ML, Bpack, f, g, expg, expg2);
  hipLaunchKernelGGL(k2b, dim3(256), dim3(512), 0, stream,
                     ML, Bpack, g, f, Upack, Av, Cv);
  hipLaunchKernelGGL(k3,  dim3(256), dim3(512), 0, stream,
                     ML, Upack, f, expg, expg2, Av, Cv, out);
}